// Round 10
// baseline (3577.876 us; speedup 1.0000x reference)
//
#include <hip/hip_runtime.h>
#include <math.h>

// BiometricLSTM: 2-layer LSTM, B=512, T=2048, I=3, H=64, fp32 in/out. Output = final h2 (B,64).
//
// R10: specialization with tax-free registers. Unified-budget law (fits R1-R9):
// budget = 1024/waves_per_block unified regs; arch share lands ~112-128 for
// 4-wave blocks, and AGPR-resident weight operands cost ~1 extra VALU move per
// use (R8: 96 half2 -> ~320 instr/wave-iter; R9 heavy: 128 half2 -> worse).
// Fix: 8-wave blocks (budget 128) with SIX dot-waves of exactly 64 weight regs
// (one matrix x K-half x 4 gates each) + TWO weightless updater waves.
// Demand ~108 <= 128 -> all-arch, no moves, no spill.
//
// 512 blocks x 512 threads (8 waves), 1 seq/block, 2 blocks/CU (4 waves/SIMD
// x 128 VGPR = full file). Wave roles (SIMD = wid&3; updaters both on SIMD3):
//   wid0: L0 dot k[0,32)   (Whh0 . h1[prev])  -> pL0[0]
//   wid1: L0 dot k[32,64)                     -> pL0[1]
//   wid2: L1-ih dot k[0,32) (Wih1 . h1[prev]) -> pL1[0][0]
//   wid4: L1-ih dot k[32,64)                  -> pL1[0][1]
//   wid5: L1-hh dot k[0,32) (Whh1 . h2[cur])  -> pL1[1][0]
//   wid6: L1-hh dot k[32,64)                  -> pL1[1][1]
//   wid3: L0 update (holds Wih0 + bias0): partials + x-proj -> act -> c0,h1
//   wid7: L1 update (holds bias1): 4 partial vectors -> act -> c1,h2, out
// Lag-1 pipeline, 2 barriers/iter, parities identical to R8 (proven).
// h kept f16 in LDS; dots via v_dot2_f32_f16 (f32 accumulate).

typedef _Float16 half2_t __attribute__((ext_vector_type(2)));

constexpr int TT = 2048;

__device__ __forceinline__ float fast_sigmoid(float x) {
    return 1.0f / (1.0f + __expf(-x));
}

// overflow-safe tanh: c can reach O(100s); exp(-2|x|) underflows harmlessly to 0 -> +/-1
__device__ __forceinline__ float fast_tanh(float x) {
    float ax = fabsf(x);
    float t  = __expf(-2.0f * ax);
    return copysignf((1.0f - t) / (1.0f + t), x);
}

__device__ __forceinline__ float dot2acc(half2_t a, half2_t b, float c) {
#if __has_builtin(__builtin_amdgcn_fdot2)
    return __builtin_amdgcn_fdot2(a, b, c, false);
#else
    c = fmaf((float)a[0], (float)b[0], c);
    return fmaf((float)a[1], (float)b[1], c);
#endif
}

__device__ __forceinline__ half2_t h2cast(float v) {
    return __builtin_bit_cast(half2_t, v);
}

__global__ __launch_bounds__(512) void lstm2_fused(
    const float* __restrict__ x,
    const float* __restrict__ Wih0, const float* __restrict__ Whh0,
    const float* __restrict__ bih0, const float* __restrict__ bhh0,
    const float* __restrict__ Wih1, const float* __restrict__ Whh1,
    const float* __restrict__ bih1, const float* __restrict__ bhh1,
    float* __restrict__ out)
{
    __shared__ __align__(16) float    xs4[TT * 4];        // 32 KB, stride-4 x
    __shared__ __align__(16) _Float16 h1buf[2][64];       // [parity][elem]
    __shared__ __align__(16) _Float16 h2buf[2][64];
    __shared__ __align__(16) float    pL0[2][64][4];      // [kappa][lane][gate]
    __shared__ __align__(16) float    pL1[2][2][64][4];   // [m][kappa][lane][gate]

    const int tid  = threadIdx.x;
    const int lane = tid & 63;
    const int wid  = tid >> 6;

    // ---- preload x: global (T,3) packed -> LDS stride 4 ----
    {
        const float* xg = x + (size_t)blockIdx.x * (TT * 3);
        for (int idx = tid; idx < TT * 3; idx += 512) {
            int t = idx / 3;              // magic-mul, no HW divide
            int c = idx - 3 * t;
            xs4[t * 4 + c] = xg[idx];
        }
    }
    // ---- zero h double-buffers (256 halves total) ----
    if (tid < 128)          ((_Float16*)h1buf)[tid] = (_Float16)0.0f;
    else if (tid < 256)     ((_Float16*)h2buf)[tid - 128] = (_Float16)0.0f;

    // ---- role setup ----
    const bool is_dot  = (wid != 3) && (wid != 7);
    const int  kap     = (wid == 1 || wid == 4 || wid == 6) ? 1 : 0;   // K-half
    const bool use_h1  = (wid <= 2 || wid == 4);                        // else h2

    half2_t w[4][16];     // dot waves: 4 gate-rows x 32 elems (K-half) = 64 regs
    float   wx[4][3];     // wid3 only
    float   bias[4];      // wid3: bias0; wid7: bias1

    if (is_dot) {
        const float* Wsrc = (wid <= 1) ? Whh0 : (use_h1 ? Wih1 : Whh1);
        #pragma unroll
        for (int g = 0; g < 4; ++g) {
            const float* rowp = Wsrc + (size_t)(g * 64 + lane) * 64 + kap * 32;
            const float4* r4 = (const float4*)rowp;
            #pragma unroll
            for (int u = 0; u < 8; ++u) {
                float4 v = r4[u];
                w[g][2*u+0] = half2_t{(_Float16)v.x, (_Float16)v.y};
                w[g][2*u+1] = half2_t{(_Float16)v.z, (_Float16)v.w};
            }
        }
    } else if (wid == 3) {
        #pragma unroll
        for (int g = 0; g < 4; ++g) {
            const int row = g * 64 + lane;
            wx[g][0] = Wih0[row*3+0]; wx[g][1] = Wih0[row*3+1]; wx[g][2] = Wih0[row*3+2];
            bias[g] = bih0[row] + bhh0[row];
        }
    } else {
        #pragma unroll
        for (int g = 0; g < 4; ++g) {
            const int row = g * 64 + lane;
            bias[g] = bih1[row] + bhh1[row];
        }
    }

    float c_state = 0.0f;     // wid3: c0[lane]; wid7: c1[lane]

    __syncthreads();

    // iter it: L0 dots step it (h1[it-1]=h1buf[prev]); L1 dots step it-1
    // (ih: h1[it-1]=h1buf[prev]; hh: h2[it-2]=h2buf[cur]). Updates: L0 writes
    // h1[it]->h1buf[cur] (it<TT); L1 writes h2[it-1]->h2buf[prev] (it>=1),
    // final output at it==TT. Edge dots run unconditionally on zeroed buffers.
    for (int it = 0; it <= TT; ++it) {
        const int cur  = it & 1;
        const int prev = cur ^ 1;

        // ---------------- phase 1: six dot waves ----------------
        if (is_dot) {
            const float4* hp = use_h1 ? (const float4*)h1buf[prev]
                                      : (const float4*)h2buf[cur];
            hp += kap * 4;                    // this wave's 32-elem half (64 B)
            float4 v0 = hp[0], v1 = hp[1], v2 = hp[2], v3 = hp[3];
            half2_t h[16];
            h[0]=h2cast(v0.x); h[1]=h2cast(v0.y); h[2]=h2cast(v0.z); h[3]=h2cast(v0.w);
            h[4]=h2cast(v1.x); h[5]=h2cast(v1.y); h[6]=h2cast(v1.z); h[7]=h2cast(v1.w);
            h[8]=h2cast(v2.x); h[9]=h2cast(v2.y); h[10]=h2cast(v2.z); h[11]=h2cast(v2.w);
            h[12]=h2cast(v3.x); h[13]=h2cast(v3.y); h[14]=h2cast(v3.z); h[15]=h2cast(v3.w);

            float pr[4];
            #pragma unroll
            for (int g = 0; g < 4; ++g) {
                float a = 0.f, b = 0.f;
                #pragma unroll
                for (int c = 0; c < 8; ++c) {
                    a = dot2acc(h[2*c+0], w[g][2*c+0], a);
                    b = dot2acc(h[2*c+1], w[g][2*c+1], b);
                }
                pr[g] = a + b;
            }
            float4 pv = make_float4(pr[0], pr[1], pr[2], pr[3]);
            if (wid <= 1) {
                ((float4*)pL0[kap])[lane] = pv;
            } else {
                const int m = use_h1 ? 0 : 1;
                ((float4*)pL1[m][kap])[lane] = pv;
            }
        }
        __syncthreads();

        // ---------------- phase 2: two updater waves ----------------
        if (wid == 3) {
            if (it < TT) {
                float4 p0 = ((const float4*)pL0[0])[lane];
                float4 p1 = ((const float4*)pL0[1])[lane];
                float4 xv = ((const float4*)xs4)[it];
                float pi = p0.x + p1.x + bias[0] + wx[0][0]*xv.x + wx[0][1]*xv.y + wx[0][2]*xv.z;
                float pf = p0.y + p1.y + bias[1] + wx[1][0]*xv.x + wx[1][1]*xv.y + wx[1][2]*xv.z;
                float pg = p0.z + p1.z + bias[2] + wx[2][0]*xv.x + wx[2][1]*xv.y + wx[2][2]*xv.z;
                float po = p0.w + p1.w + bias[3] + wx[3][0]*xv.x + wx[3][1]*xv.y + wx[3][2]*xv.z;
                float iv = fast_sigmoid(pi), fv = fast_sigmoid(pf);
                float gv = fast_tanh(pg),    ov = fast_sigmoid(po);
                c_state = fmaf(fv, c_state, iv * gv);
                h1buf[cur][lane] = (_Float16)(ov * fast_tanh(c_state));   // h1[it]
            }
        } else if (wid == 7) {
            if (it >= 1) {
                float4 a0 = ((const float4*)pL1[0][0])[lane];
                float4 a1 = ((const float4*)pL1[0][1])[lane];
                float4 b0 = ((const float4*)pL1[1][0])[lane];
                float4 b1 = ((const float4*)pL1[1][1])[lane];
                float pi = a0.x + a1.x + b0.x + b1.x + bias[0];
                float pf = a0.y + a1.y + b0.y + b1.y + bias[1];
                float pg = a0.z + a1.z + b0.z + b1.z + bias[2];
                float po = a0.w + a1.w + b0.w + b1.w + bias[3];
                float iv = fast_sigmoid(pi), fv = fast_sigmoid(pf);
                float gv = fast_tanh(pg),    ov = fast_sigmoid(po);
                c_state = fmaf(fv, c_state, iv * gv);
                float hv = ov * fast_tanh(c_state);
                h2buf[prev][lane] = (_Float16)hv;                         // h2[it-1]
                if (it == TT)
                    out[(size_t)blockIdx.x * 64 + lane] = hv;
            }
        }
        __syncthreads();
    }
}

extern "C" void kernel_launch(void* const* d_in, const int* in_sizes, int n_in,
                              void* d_out, int out_size, void* d_ws, size_t ws_size,
                              hipStream_t stream) {
    const float* x    = (const float*)d_in[0];
    const float* Wih0 = (const float*)d_in[1];
    const float* Whh0 = (const float*)d_in[2];
    const float* bih0 = (const float*)d_in[3];
    const float* bhh0 = (const float*)d_in[4];
    const float* Wih1 = (const float*)d_in[5];
    const float* Whh1 = (const float*)d_in[6];
    const float* bih1 = (const float*)d_in[7];
    const float* bhh1 = (const float*)d_in[8];
    float* out = (float*)d_out;

    // 512 sequences, 1 per block -> 512 blocks; 512 threads (8 waves).
    // 2 blocks/CU if VGPR<=128 (4 waves/SIMD x 128 = full file).
    lstm2_fused<<<512, 512, 0, stream>>>(x, Wih0, Whh0, bih0, bhh0,
                                         Wih1, Whh1, bih1, bhh1, out);
}